// Round 1
// baseline (230011.426 us; speedup 1.0000x reference)
//
#include <hip/hip_runtime.h>

// ---------------- problem constants ----------------
#define BATCH 512
#define SEQL  512
#define HID   256
#define MF    17
#define G4    1024          // 4*HID gate rows
#define KX    512           // folded x dim: [z(256), h(256)]
#define PBLK  16            // blocks (slices) per group
#define NGRP  16            // groups (each owns 32 batch rows)
#define BG    32            // batch rows per group
#define NTHR  512

// ---------------- workspace layout (float offsets) ----------------
#define WS_WC  ((size_t)0)                       // folded+reordered weights [1024][512]
#define WS_BC  (WS_WC + (size_t)G4*KX)           // folded bias [1024]
#define WS_C0  (WS_BC + (size_t)G4)              // step-0 correction [B][1024]
#define WS_HB  (WS_C0 + (size_t)BATCH*G4)        // h double buffer [2][B][256]
#define WS_CNT (WS_HB + (size_t)2*BATCH*HID)     // sync counters (ints), 32-int stride per group
#define WS_END (WS_CNT + 1024)

// ---------------- LDS layout (float offsets) ----------------
#define WLPAD  516
#define L_WL   0                       // [64][516] weight slice
#define L_XS   (64*WLPAD)              // [2][32][68] x chunk double buffer (buf0 aliased by Gs)
#define L_GS   L_XS                    // [64][33] gates gather (alias of xs buf0 — hazard-free, see barriers)
#define L_HST  (L_XS + 2*32*68)        // [16][33] h transpose staging
#define LDS_FLOATS (L_HST + 16*33)     // 37904 floats
#define LDS_BYTES  (LDS_FLOATS*4)      // 151616 B  (<160KB/CU -> 1 block/CU)

// ============================================================
// K1: build folded & row-reordered weights Wc[rho][512] and bias bc[rho]
//   rho(r): r = g*256+u, s=u>>4  ->  rho = s*64 + g*16 + (u&15)
//   k<256: Wz = W_ih[:,17+k]; k>=256: W_hh + W_ih[:,:17] @ W_lin
// ============================================================
__global__ void k_fold(const float* __restrict__ Wih, const float* __restrict__ Whh,
                       const float* __restrict__ bih, const float* __restrict__ bhh,
                       const float* __restrict__ Wlin, const float* __restrict__ blin,
                       float* __restrict__ ws)
{
    int r = blockIdx.x;               // 0..1023 original gate row
    int g = r >> 8;
    int u = r & 255;
    int s = u >> 4;
    int rho = s*64 + g*16 + (u & 15);
    __shared__ float wrow[17];
    int tid = threadIdx.x;            // 128
    if (tid < 17) wrow[tid] = Wih[(size_t)r*273 + tid];
    __syncthreads();
    float* Wc = ws + WS_WC + (size_t)rho*KX;
    for (int k = tid; k < KX; k += 128) {
        float v;
        if (k < 256) {
            v = Wih[(size_t)r*273 + 17 + k];
        } else {
            int kk = k - 256;
            v = Whh[(size_t)r*256 + kk];
            #pragma unroll
            for (int m = 0; m < 17; ++m) v += wrow[m]*Wlin[m*256 + kk];
        }
        Wc[k] = v;
    }
    if (tid == 0) {
        float b = bih[r] + bhh[r];
        #pragma unroll
        for (int m = 0; m < 17; ++m) b += wrow[m]*blin[m];
        ws[WS_BC + rho] = b;
    }
}

// ============================================================
// K2: step-0 correction C0[b][rho] = W_ih[:,:17] @ (W_lin@h0_b + b_lin)
// ============================================================
__global__ void k_c0(const float* __restrict__ Wih, const float* __restrict__ Wlin,
                     const float* __restrict__ blin, const float* __restrict__ h0,
                     float* __restrict__ ws)
{
    int b = blockIdx.x;               // 0..511
    int tid = threadIdx.x;            // 256
    __shared__ float part[17][8];
    __shared__ float t0[17];
    if (tid < 136) {
        int m = tid >> 3, p = tid & 7;
        const float* h = h0 + (size_t)b*256;
        float sacc = 0.f;
        for (int k = p*32; k < p*32 + 32; ++k) sacc += Wlin[m*256 + k]*h[k];
        part[m][p] = sacc;
    }
    __syncthreads();
    if (tid < 17) {
        float sacc = blin[tid];
        #pragma unroll
        for (int p = 0; p < 8; ++p) sacc += part[tid][p];
        t0[tid] = sacc;
    }
    __syncthreads();
    for (int rho = tid; rho < G4; rho += 256) {
        int s_ = rho >> 6;
        int g  = (rho >> 4) & 3;
        int ul = rho & 15;
        int r  = g*256 + s_*16 + ul;
        float v = 0.f;
        #pragma unroll
        for (int m = 0; m < 17; ++m) v += Wih[(size_t)r*273 + m]*t0[m];
        ws[WS_C0 + (size_t)b*G4 + rho] = v;
    }
}

// ============================================================
// Main persistent LSTM kernel. 256 blocks x 512 threads, cooperative.
// block -> (group gg, slice s). Group = 16 blocks sharing 32 batch rows.
// Heuristic XCD-contiguous mapping (correctness does NOT depend on it:
// sync uses agent-scope release/acquire fences).
// ============================================================
__global__ void __launch_bounds__(NTHR) k_lstm(
    const float* __restrict__ inseq, const float* __restrict__ h0,
    const float* __restrict__ c0,   const float* __restrict__ Wlin,
    const float* __restrict__ blin, float* __restrict__ ws,
    float* __restrict__ out)
{
    extern __shared__ float lds[];
    float* Wl  = lds + L_WL;
    float* xsb = lds + L_XS;
    float* Gs  = lds + L_GS;     // alias of xs buf0
    float* hst = lds + L_HST;

    const int bid = blockIdx.x;
    const int xcd = bid & 7, j = bid >> 3;
    const int gg  = xcd + 8*(j >> 4);   // 0..15 group
    const int s   = j & 15;             // 0..15 slice
    const int tid = threadIdx.x;

    // ---- stage weight slice into LDS: rows rho in [64s, 64s+64) ----
    {
        int row = tid >> 3, seg = tid & 7;
        const float* src = ws + WS_WC + (size_t)(s*64 + row)*KX + seg*64;
        float* dst = Wl + row*WLPAD + seg*64;
        #pragma unroll
        for (int i = 0; i < 64; i += 4)
            *(float4*)(dst + i) = *(const float4*)(src + i);
    }

    // ---- per-thread constants ----
    // update mapping: unit uu (0..15), batch ub (0..31)
    const int uu = tid >> 5;
    const int ub = tid & 31;
    float bc4[4], c04[4];
    #pragma unroll
    for (int g = 0; g < 4; ++g) bc4[g] = ws[WS_BC + s*64 + g*16 + uu];
    #pragma unroll
    for (int g = 0; g < 4; ++g) c04[g] = ws[WS_C0 + (size_t)(gg*32 + ub)*G4 + s*64 + g*16 + uu];
    float creg = c0[(size_t)(gg*32 + ub)*256 + s*16 + uu];

    // staging mapping: batch bb (0..31), k-quad kq (0..15)
    const int bb = tid >> 4;
    const int kq = tid & 15;
    // W_lin rows for fused out head: block s computes m=s; block 0 also m=16
    float4 wl1[4], wl2[4];
    #pragma unroll
    for (int cc = 0; cc < 4; ++cc) {
        int kh = cc*64 + 4*kq;
        wl1[cc] = *(const float4*)(Wlin + s*256 + kh);
        if (s == 0) wl2[cc] = *(const float4*)(Wlin + 16*256 + kh);
        else        wl2[cc] = make_float4(0.f,0.f,0.f,0.f);
    }

    // gemm mapping: row pair rg (0..31), batch bp (0..15)
    const int rg = tid >> 4;
    const int bp = tid & 15;
    const float* wrow0 = Wl + (2*rg)*WLPAD;
    const float* wrow1 = Wl + (2*rg + 1)*WLPAD;

    int* cnt = (int*)(ws + WS_CNT) + gg*32;   // own cacheline per group
    const float* zbase = inseq + (size_t)(gg*32)*SEQL*HID;
    float* hb = ws + WS_HB;

    float oacc1 = 0.f, oacc2 = 0.f;
    __syncthreads();   // Wl ready

    for (int t = 0; t < SEQL; ++t) {
        const float* hsrc = (t == 0)
            ? (h0 + (size_t)(gg*32)*HID)
            : (hb + (size_t)((t & 1) ^ 1)*BATCH*HID + (size_t)(gg*32)*HID);

        // stage chunk 0 (z part)
        {
            float4 v = *(const float4*)(zbase + (size_t)bb*SEQL*HID + (size_t)t*HID + 4*kq);
            *(float4*)(xsb + bb*68 + 4*kq) = v;
        }
        __syncthreads();

        float a00 = 0.f, a01 = 0.f, a10 = 0.f, a11 = 0.f;
        #pragma unroll
        for (int c = 0; c < 8; ++c) {
            // stage chunk c+1 into the other buffer (overlaps gemm(c))
            if (c < 7) {
                const int cn = c + 1;
                float* xbn = xsb + (cn & 1)*(32*68);
                float4 v;
                if (cn < 4) {
                    v = *(const float4*)(zbase + (size_t)bb*SEQL*HID + (size_t)t*HID + cn*64 + 4*kq);
                } else {
                    v = *(const float4*)(hsrc + (size_t)bb*HID + (cn - 4)*64 + 4*kq);
                    const int cc = cn - 4;   // fused out head: out_{t-1} partial
                    oacc1 += v.x*wl1[cc].x + v.y*wl1[cc].y + v.z*wl1[cc].z + v.w*wl1[cc].w;
                    if (s == 0)
                        oacc2 += v.x*wl2[cc].x + v.y*wl2[cc].y + v.z*wl2[cc].z + v.w*wl2[cc].w;
                }
                *(float4*)(xbn + bb*68 + 4*kq) = v;
            }
            // gemm on chunk c
            {
                const float* xbc = xsb + (c & 1)*(32*68);
                const float* w0 = wrow0 + c*64;
                const float* w1 = wrow1 + c*64;
                const float* x0p = xbc + bp*68;
                const float* x1p = xbc + (bp + 16)*68;
                #pragma unroll
                for (int k = 0; k < 64; k += 4) {
                    float4 wa = *(const float4*)(w0 + k);
                    float4 wb = *(const float4*)(w1 + k);
                    float4 x0 = *(const float4*)(x0p + k);
                    float4 x1 = *(const float4*)(x1p + k);
                    a00 = fmaf(wa.x,x0.x, fmaf(wa.y,x0.y, fmaf(wa.z,x0.z, fmaf(wa.w,x0.w, a00))));
                    a01 = fmaf(wa.x,x1.x, fmaf(wa.y,x1.y, fmaf(wa.z,x1.z, fmaf(wa.w,x1.w, a01))));
                    a10 = fmaf(wb.x,x0.x, fmaf(wb.y,x0.y, fmaf(wb.z,x0.z, fmaf(wb.w,x0.w, a10))));
                    a11 = fmaf(wb.x,x1.x, fmaf(wb.y,x1.y, fmaf(wb.z,x1.z, fmaf(wb.w,x1.w, a11))));
                }
            }
            __syncthreads();
        }

        // out_{t-1}: reduce over kq (16-lane groups), store
        {
            float r1 = oacc1, r2 = oacc2;
            #pragma unroll
            for (int off = 8; off; off >>= 1) {
                r1 += __shfl_xor(r1, off, 16);
                if (s == 0) r2 += __shfl_xor(r2, off, 16);
            }
            if (t > 0 && kq == 0) {
                float* o = out + ((size_t)(gg*32 + bb)*SEQL + (t - 1))*MF;
                o[s] = r1 + blin[s];
                if (s == 0) o[16] = r2 + blin[16];
            }
            oacc1 = 0.f; oacc2 = 0.f;
        }

        // gather gates (Gs aliases xs buf0; all gemm reads completed at last barrier)
        Gs[(2*rg)*33 + bp]        = a00;
        Gs[(2*rg)*33 + bp + 16]   = a01;
        Gs[(2*rg + 1)*33 + bp]      = a10;
        Gs[(2*rg + 1)*33 + bp + 16] = a11;
        __syncthreads();

        // cell update for (unit uu, batch ub)
        {
            float ig = Gs[(  0 + uu)*33 + ub] + bc4[0];
            float fg = Gs[( 16 + uu)*33 + ub] + bc4[1];
            float gv = Gs[( 32 + uu)*33 + ub] + bc4[2];
            float og = Gs[( 48 + uu)*33 + ub] + bc4[3];
            if (t == 0) { ig -= c04[0]; fg -= c04[1]; gv -= c04[2]; og -= c04[3]; }
            float si = 1.f/(1.f + __expf(-ig));
            float sf = 1.f/(1.f + __expf(-fg));
            float so = 1.f/(1.f + __expf(-og));
            float tg = tanhf(gv);
            creg = sf*creg + si*tg;
            float h = so*tanhf(creg);
            hst[uu*33 + ub] = h;
        }
        __syncthreads();

        // coalesced h write: 16 contiguous floats per batch row
        {
            int b2 = tid >> 4, u2 = tid & 15;
            hb[(size_t)(t & 1)*BATCH*HID + (size_t)(gg*32 + b2)*HID + s*16 + u2] = hst[u2*33 + b2];
        }
        __syncthreads();

        // group sync: release own h slice, wait for the other 15 slices
        if (tid == 0) {
            __builtin_amdgcn_fence(__ATOMIC_RELEASE, "agent");
            __hip_atomic_fetch_add(cnt, 1, __ATOMIC_RELAXED, __HIP_MEMORY_SCOPE_AGENT);
            const int target = PBLK*(t + 1);
            while (__hip_atomic_load(cnt, __ATOMIC_RELAXED, __HIP_MEMORY_SCOPE_AGENT) < target)
                __builtin_amdgcn_s_sleep(2);
            __builtin_amdgcn_fence(__ATOMIC_ACQUIRE, "agent");
        }
        __syncthreads();
    }

    // epilogue: out_511 from hb[1]
    {
        const float* hfin = hb + (size_t)1*BATCH*HID + (size_t)(gg*32)*HID;
        float r1 = 0.f, r2 = 0.f;
        #pragma unroll
        for (int cc = 0; cc < 4; ++cc) {
            float4 v = *(const float4*)(hfin + (size_t)bb*HID + cc*64 + 4*kq);
            r1 += v.x*wl1[cc].x + v.y*wl1[cc].y + v.z*wl1[cc].z + v.w*wl1[cc].w;
            if (s == 0)
                r2 += v.x*wl2[cc].x + v.y*wl2[cc].y + v.z*wl2[cc].z + v.w*wl2[cc].w;
        }
        #pragma unroll
        for (int off = 8; off; off >>= 1) {
            r1 += __shfl_xor(r1, off, 16);
            r2 += __shfl_xor(r2, off, 16);
        }
        if (kq == 0) {
            float* o = out + ((size_t)(gg*32 + bb)*SEQL + (SEQL - 1))*MF;
            o[s] = r1 + blin[s];
            if (s == 0) o[16] = r2 + blin[16];
        }
    }
}

// ============================================================
extern "C" void kernel_launch(void* const* d_in, const int* in_sizes, int n_in,
                              void* d_out, int out_size, void* d_ws, size_t ws_size,
                              hipStream_t stream)
{
    const float* inseq = (const float*)d_in[0];
    const float* h0    = (const float*)d_in[1];
    const float* c0    = (const float*)d_in[2];
    const float* Wih   = (const float*)d_in[3];
    const float* Whh   = (const float*)d_in[4];
    const float* bih   = (const float*)d_in[5];
    const float* bhh   = (const float*)d_in[6];
    const float* Wlin  = (const float*)d_in[7];
    const float* blin  = (const float*)d_in[8];
    float* outp = (float*)d_out;
    float* ws   = (float*)d_ws;

    // allow >64KB dynamic LDS for the persistent kernel
    static bool attr_set = false;
    if (!attr_set) {
        hipFuncSetAttribute((const void*)k_lstm,
                            hipFuncAttributeMaxDynamicSharedMemorySize, LDS_BYTES);
        attr_set = true;
    }

    // zero group sync counters (d_ws is re-poisoned before every launch)
    hipMemsetAsync((char*)d_ws + WS_CNT*sizeof(float), 0, 1024*sizeof(int), stream);

    k_fold<<<dim3(G4), dim3(128), 0, stream>>>(Wih, Whh, bih, bhh, Wlin, blin, ws);
    k_c0  <<<dim3(BATCH), dim3(256), 0, stream>>>(Wih, Wlin, blin, h0, ws);

    void* fp_in  = (void*)inseq; void* fp_h0 = (void*)h0; void* fp_c0 = (void*)c0;
    void* fp_wl  = (void*)Wlin;  void* fp_bl = (void*)blin;
    void* fp_ws  = (void*)ws;    void* fp_o  = (void*)outp;
    void* args[7] = { &fp_in, &fp_h0, &fp_c0, &fp_wl, &fp_bl, &fp_ws, &fp_o };
    hipLaunchCooperativeKernel((const void*)k_lstm, dim3(256), dim3(NTHR),
                               args, LDS_BYTES, stream);
}

// Round 3
// 203079.004 us; speedup vs baseline: 1.1326x; 1.1326x over previous
//
#include <hip/hip_runtime.h>

// ---------------- problem constants ----------------
#define BATCH 512
#define SEQL  512
#define HID   256
#define MF    17
#define G4    1024          // 4*HID gate rows
#define KX    512           // folded x dim: [z(256), h(256)]
#define PBLK  16            // blocks (slices) per group
#define NGRP  16            // groups (each owns 32 batch rows)
#define BG    32            // batch rows per group
#define NTHR  512

// ---------------- workspace layout (float offsets) ----------------
#define WS_WC  ((size_t)0)                       // folded+reordered weights [1024][512]
#define WS_BC  (WS_WC + (size_t)G4*KX)           // folded bias [1024]
#define WS_C0  (WS_BC + (size_t)G4)              // step-0 correction [B][1024]
#define WS_HB  (WS_C0 + (size_t)BATCH*G4)        // h double buffer [2][B][256]
#define WS_CNT (WS_HB + (size_t)2*BATCH*HID)     // sync counters (ints), 32-int stride per group
#define WS_END (WS_CNT + 1024)

// ---------------- LDS layout (float offsets) ----------------
#define WLPAD  517                     // ks-stride-4 W reads: max 2-way (free)
#define XPAD   68
#define L_WL   0                       // [64][517] weight slice
#define L_XS   (64*WLPAD)              // [2][32][68] x chunk double buffer (buf0 aliased by Gs)
#define L_GS   L_XS                    // [64][33] gates gather (alias of xs buf0 — hazard-free, see barriers)
#define L_HST  (L_XS + 2*32*XPAD)      // [16][33] h transpose staging
#define LDS_FLOATS (L_HST + 16*33)     // 37968 floats
#define LDS_BYTES  (LDS_FLOATS*4)      // 151872 B  (<160KB/CU -> 1 block/CU)

#define AT_LD(p)    __hip_atomic_load((p), __ATOMIC_RELAXED, __HIP_MEMORY_SCOPE_AGENT)
#define AT_ST(p, v) __hip_atomic_store((p), (v), __ATOMIC_RELAXED, __HIP_MEMORY_SCOPE_AGENT)

// ============================================================
// K1: build folded & row-reordered weights Wc[rho][512] and bias bc[rho]
//   rho(r): r = g*256+u, s=u>>4  ->  rho = s*64 + g*16 + (u&15)
//   k<256: Wz = W_ih[:,17+k]; k>=256: W_hh + W_ih[:,:17] @ W_lin
// ============================================================
__global__ void k_fold(const float* __restrict__ Wih, const float* __restrict__ Whh,
                       const float* __restrict__ bih, const float* __restrict__ bhh,
                       const float* __restrict__ Wlin, const float* __restrict__ blin,
                       float* __restrict__ ws)
{
    int r = blockIdx.x;               // 0..1023 original gate row
    int g = r >> 8;
    int u = r & 255;
    int s = u >> 4;
    int rho = s*64 + g*16 + (u & 15);
    __shared__ float wrow[17];
    int tid = threadIdx.x;            // 128
    if (tid < 17) wrow[tid] = Wih[(size_t)r*273 + tid];
    __syncthreads();
    float* Wc = ws + WS_WC + (size_t)rho*KX;
    for (int k = tid; k < KX; k += 128) {
        float v;
        if (k < 256) {
            v = Wih[(size_t)r*273 + 17 + k];
        } else {
            int kk = k - 256;
            v = Whh[(size_t)r*256 + kk];
            #pragma unroll
            for (int m = 0; m < 17; ++m) v += wrow[m]*Wlin[m*256 + kk];
        }
        Wc[k] = v;
    }
    if (tid == 0) {
        float b = bih[r] + bhh[r];
        #pragma unroll
        for (int m = 0; m < 17; ++m) b += wrow[m]*blin[m];
        ws[WS_BC + rho] = b;
    }
}

// ============================================================
// K2: step-0 correction C0[b][rho] = W_ih[:,:17] @ (W_lin@h0_b + b_lin)
// ============================================================
__global__ void k_c0(const float* __restrict__ Wih, const float* __restrict__ Wlin,
                     const float* __restrict__ blin, const float* __restrict__ h0,
                     float* __restrict__ ws)
{
    int b = blockIdx.x;               // 0..511
    int tid = threadIdx.x;            // 256
    __shared__ float part[17][8];
    __shared__ float t0[17];
    if (tid < 136) {
        int m = tid >> 3, p = tid & 7;
        const float* h = h0 + (size_t)b*256;
        float sacc = 0.f;
        for (int k = p*32; k < p*32 + 32; ++k) sacc += Wlin[m*256 + k]*h[k];
        part[m][p] = sacc;
    }
    __syncthreads();
    if (tid < 17) {
        float sacc = blin[tid];
        #pragma unroll
        for (int p = 0; p < 8; ++p) sacc += part[tid][p];
        t0[tid] = sacc;
    }
    __syncthreads();
    for (int rho = tid; rho < G4; rho += 256) {
        int s_ = rho >> 6;
        int g  = (rho >> 4) & 3;
        int ul = rho & 15;
        int r  = g*256 + s_*16 + ul;
        float v = 0.f;
        #pragma unroll
        for (int m = 0; m < 17; ++m) v += Wih[(size_t)r*273 + m]*t0[m];
        ws[WS_C0 + (size_t)b*G4 + rho] = v;
    }
}

// ============================================================
// Main persistent LSTM kernel. 256 blocks x 512 threads, cooperative.
// block -> (group gg, slice s). Group = 16 blocks sharing 32 batch rows.
//
// Cross-block exchange: ALL shared data (hb) moves via relaxed agent-scope
// atomics (sc0 sc1 -> bypass L1/L2 to the MALL coherence point).
// NO agent fences anywhere: round-1's fences compiled to buffer_wbl2/inv
// (full L2 flush per block per step -> 475 GB writeback = the 230 ms).
// Ordering: sc1 stores -> __syncthreads (compiler drains vmcnt(0) for ALL
// waves before s_barrier) -> relaxed flag add -> consumer spins on relaxed
// sc1 load. MALL is a single coherence point, so flag-after-data suffices.
//
// The spin is BOUNDED (2^16 polls): a true deadlock degrades into a
// finishing-but-wrong run with full counters instead of a wedged container.
// ============================================================
__global__ void __launch_bounds__(NTHR) k_lstm(
    const float* __restrict__ inseq, const float* __restrict__ h0,
    const float* __restrict__ c0,   const float* __restrict__ Wlin,
    const float* __restrict__ blin, float* __restrict__ ws,
    float* __restrict__ out)
{
    extern __shared__ float lds[];
    float* Wl  = lds + L_WL;
    float* xsb = lds + L_XS;
    float* Gs  = lds + L_GS;     // alias of xs buf0
    float* hst = lds + L_HST;

    const int bid = blockIdx.x;
    const int xcd = bid & 7, j = bid >> 3;
    const int gg  = xcd + 8*(j >> 4);   // 0..15 group
    const int s   = j & 15;             // 0..15 slice
    const int tid = threadIdx.x;

    // ---- stage weight slice into LDS: rows rho in [64s, 64s+64) ----
    {
        int row = tid >> 3, seg = tid & 7;
        const float* src = ws + WS_WC + (size_t)(s*64 + row)*KX + seg*64;
        float* dst = Wl + row*WLPAD + seg*64;
        #pragma unroll
        for (int i = 0; i < 64; i += 4)
            *(float4*)(dst + i) = *(const float4*)(src + i);
    }

    // ---- per-thread constants ----
    // update mapping: unit uu (0..15), batch ub (0..31)
    const int uu = tid >> 5;
    const int ub = tid & 31;
    float bc4[4], c04[4];
    #pragma unroll
    for (int g = 0; g < 4; ++g) bc4[g] = ws[WS_BC + s*64 + g*16 + uu];
    #pragma unroll
    for (int g = 0; g < 4; ++g) c04[g] = ws[WS_C0 + (size_t)(gg*32 + ub)*G4 + s*64 + g*16 + uu];
    float creg = c0[(size_t)(gg*32 + ub)*256 + s*16 + uu];

    // staging mapping: batch bb (0..31), k-quad kq (0..15)
    const int bb = tid >> 4;
    const int kq = tid & 15;
    // W_lin rows for fused out head: block s computes m=s; block 0 also m=16
    float4 wl1[4], wl2[4];
    #pragma unroll
    for (int cc = 0; cc < 4; ++cc) {
        int kh = cc*64 + 4*kq;
        wl1[cc] = *(const float4*)(Wlin + s*256 + kh);
        if (s == 0) wl2[cc] = *(const float4*)(Wlin + 16*256 + kh);
        else        wl2[cc] = make_float4(0.f,0.f,0.f,0.f);
    }

    // gemm mapping: 4x4 tile + 4-way k-split
    //   ks = tid&3 (k-split lane), bq = (tid>>2)&7 (batch quad), rq = tid>>5 (row quad)
    const int ks = tid & 3;
    const int bq = (tid >> 2) & 7;
    const int rq = tid >> 5;

    int* cnt = (int*)(ws + WS_CNT) + gg*32;   // own cacheline per group
    const float* zbase = inseq + (size_t)(gg*32)*SEQL*HID;
    float* hb = ws + WS_HB;

    float oacc1 = 0.f, oacc2 = 0.f;
    __syncthreads();   // Wl ready

    for (int t = 0; t < SEQL; ++t) {
        const float* hsrc = (t == 0)
            ? (h0 + (size_t)(gg*32)*HID)
            : (hb + (size_t)((t & 1) ^ 1)*BATCH*HID + (size_t)(gg*32)*HID);

        // stage chunk 0 (z part)
        {
            float4 v = *(const float4*)(zbase + (size_t)bb*SEQL*HID + (size_t)t*HID + 4*kq);
            *(float4*)(xsb + bb*XPAD + 4*kq) = v;
        }
        __syncthreads();

        float acc[4][4];
        #pragma unroll
        for (int i = 0; i < 4; ++i)
            #pragma unroll
            for (int jj = 0; jj < 4; ++jj) acc[i][jj] = 0.f;

        #pragma unroll
        for (int c = 0; c < 8; ++c) {
            // stage chunk c+1 into the other buffer (overlaps gemm(c))
            if (c < 7) {
                const int cn = c + 1;
                float* xbn = xsb + (cn & 1)*(32*XPAD);
                float4 v;
                if (cn < 4) {
                    v = *(const float4*)(zbase + (size_t)bb*SEQL*HID + (size_t)t*HID + cn*64 + 4*kq);
                } else {
                    // h of other slices: written by other blocks possibly on
                    // other XCDs -> L2-bypassing relaxed agent atomic loads
                    const float* hp = hsrc + (size_t)bb*HID + (cn - 4)*64 + 4*kq;
                    v.x = AT_LD(hp + 0);
                    v.y = AT_LD(hp + 1);
                    v.z = AT_LD(hp + 2);
                    v.w = AT_LD(hp + 3);
                    const int cc = cn - 4;   // fused out head: out_{t-1} partial
                    oacc1 += v.x*wl1[cc].x + v.y*wl1[cc].y + v.z*wl1[cc].z + v.w*wl1[cc].w;
                    if (s == 0)
                        oacc2 += v.x*wl2[cc].x + v.y*wl2[cc].y + v.z*wl2[cc].z + v.w*wl2[cc].w;
                }
                *(float4*)(xbn + bb*XPAD + 4*kq) = v;
            }
            // gemm on chunk c: 4 rows x 4 batches, k-split 4 (16 k per thread)
            {
                const float* xbc = xsb + (c & 1)*(32*XPAD);
                #pragma unroll
                for (int g2 = 0; g2 < 4; ++g2) {
                    const int ko = c*64 + g2*16 + ks*4;   // column in Wl
                    const int xo = g2*16 + ks*4;          // column within chunk
                    float4 wv[4], xv[4];
                    #pragma unroll
                    for (int i = 0; i < 4; ++i)
                        wv[i] = *(const float4*)(Wl + (4*rq + i)*WLPAD + ko);
                    #pragma unroll
                    for (int jj = 0; jj < 4; ++jj)
                        xv[jj] = *(const float4*)(xbc + (4*bq + jj)*XPAD + xo);
                    #pragma unroll
                    for (int i = 0; i < 4; ++i)
                        #pragma unroll
                        for (int jj = 0; jj < 4; ++jj)
                            acc[i][jj] = fmaf(wv[i].x, xv[jj].x,
                                         fmaf(wv[i].y, xv[jj].y,
                                         fmaf(wv[i].z, xv[jj].z,
                                         fmaf(wv[i].w, xv[jj].w, acc[i][jj]))));
                }
            }
            __syncthreads();
        }

        // out_{t-1}: reduce over kq (16-lane groups), store
        {
            float r1 = oacc1, r2 = oacc2;
            #pragma unroll
            for (int off = 8; off; off >>= 1) {
                r1 += __shfl_xor(r1, off, 16);
                if (s == 0) r2 += __shfl_xor(r2, off, 16);
            }
            if (t > 0 && kq == 0) {
                float* o = out + ((size_t)(gg*32 + bb)*SEQL + (t - 1))*MF;
                o[s] = r1 + blin[s];
                if (s == 0) o[16] = r2 + blin[16];
            }
            oacc1 = 0.f; oacc2 = 0.f;
        }

        // k-split reduction (lanes ks=bits0-1, DPP-cheap) + gather gates
        // (Gs aliases xs buf0; all gemm reads completed at last barrier)
        #pragma unroll
        for (int i = 0; i < 4; ++i)
            #pragma unroll
            for (int jj = 0; jj < 4; ++jj) {
                float v = acc[i][jj];
                v += __shfl_xor(v, 1);
                v += __shfl_xor(v, 2);
                if (ks == 0) Gs[(4*rq + i)*33 + 4*bq + jj] = v;
            }
        __syncthreads();

        // cell update for (unit uu, batch ub)
        {
            float ig = Gs[(  0 + uu)*33 + ub] + bc4[0];
            float fg = Gs[( 16 + uu)*33 + ub] + bc4[1];
            float gv = Gs[( 32 + uu)*33 + ub] + bc4[2];
            float og = Gs[( 48 + uu)*33 + ub] + bc4[3];
            if (t == 0) { ig -= c04[0]; fg -= c04[1]; gv -= c04[2]; og -= c04[3]; }
            float si = 1.f/(1.f + __expf(-ig));
            float sf = 1.f/(1.f + __expf(-fg));
            float so = 1.f/(1.f + __expf(-og));
            float tg = tanhf(gv);
            creg = sf*creg + si*tg;
            float h = so*tanhf(creg);
            hst[uu*33 + ub] = h;
        }
        __syncthreads();

        // coalesced h publish: sc1 store (bypass L2 to MALL, no flush)
        {
            int b2 = tid >> 4, u2 = tid & 15;
            AT_ST(hb + (size_t)(t & 1)*BATCH*HID + (size_t)(gg*32 + b2)*HID + s*16 + u2,
                  hst[u2*33 + b2]);
        }
        __syncthreads();   // drains vmcnt(0) for ALL waves -> h visible at MALL

        // group sync: bump arrival count, wait for the other 15 slices.
        // Bounded spin: deadlock -> wrong-but-finishing run (diagnosable).
        if (tid == 0) {
            __hip_atomic_fetch_add(cnt, 1, __ATOMIC_RELAXED, __HIP_MEMORY_SCOPE_AGENT);
            const int target = PBLK*(t + 1);
            int guard = 0;
            while (__hip_atomic_load(cnt, __ATOMIC_RELAXED, __HIP_MEMORY_SCOPE_AGENT) < target
                   && guard < (1 << 16)) {
                __builtin_amdgcn_s_sleep(2);
                ++guard;
            }
        }
        __syncthreads();
    }

    // epilogue: out_511 from hb[1] (other blocks' data -> sc1 loads)
    {
        const float* hfin = hb + (size_t)1*BATCH*HID + (size_t)(gg*32)*HID;
        float r1 = 0.f, r2 = 0.f;
        #pragma unroll
        for (int cc = 0; cc < 4; ++cc) {
            const float* hp = hfin + (size_t)bb*HID + cc*64 + 4*kq;
            float4 v;
            v.x = AT_LD(hp + 0);
            v.y = AT_LD(hp + 1);
            v.z = AT_LD(hp + 2);
            v.w = AT_LD(hp + 3);
            r1 += v.x*wl1[cc].x + v.y*wl1[cc].y + v.z*wl1[cc].z + v.w*wl1[cc].w;
            if (s == 0)
                r2 += v.x*wl2[cc].x + v.y*wl2[cc].y + v.z*wl2[cc].z + v.w*wl2[cc].w;
        }
        #pragma unroll
        for (int off = 8; off; off >>= 1) {
            r1 += __shfl_xor(r1, off, 16);
            r2 += __shfl_xor(r2, off, 16);
        }
        if (kq == 0) {
            float* o = out + ((size_t)(gg*32 + bb)*SEQL + (SEQL - 1))*MF;
            o[s] = r1 + blin[s];
            if (s == 0) o[16] = r2 + blin[16];
        }
    }
}

// ============================================================
extern "C" void kernel_launch(void* const* d_in, const int* in_sizes, int n_in,
                              void* d_out, int out_size, void* d_ws, size_t ws_size,
                              hipStream_t stream)
{
    const float* inseq = (const float*)d_in[0];
    const float* h0    = (const float*)d_in[1];
    const float* c0    = (const float*)d_in[2];
    const float* Wih   = (const float*)d_in[3];
    const float* Whh   = (const float*)d_in[4];
    const float* bih   = (const float*)d_in[5];
    const float* bhh   = (const float*)d_in[6];
    const float* Wlin  = (const float*)d_in[7];
    const float* blin  = (const float*)d_in[8];
    float* outp = (float*)d_out;
    float* ws   = (float*)d_ws;

    // allow >64KB dynamic LDS for the persistent kernel
    static bool attr_set = false;
    if (!attr_set) {
        hipFuncSetAttribute((const void*)k_lstm,
                            hipFuncAttributeMaxDynamicSharedMemorySize, LDS_BYTES);
        attr_set = true;
    }

    // zero group sync counters (d_ws is re-poisoned before every launch)
    hipMemsetAsync((char*)d_ws + WS_CNT*sizeof(float), 0, 1024*sizeof(int), stream);

    k_fold<<<dim3(G4), dim3(128), 0, stream>>>(Wih, Whh, bih, bhh, Wlin, blin, ws);
    k_c0  <<<dim3(BATCH), dim3(256), 0, stream>>>(Wih, Wlin, blin, h0, ws);

    void* fp_in  = (void*)inseq; void* fp_h0 = (void*)h0; void* fp_c0 = (void*)c0;
    void* fp_wl  = (void*)Wlin;  void* fp_bl = (void*)blin;
    void* fp_ws  = (void*)ws;    void* fp_o  = (void*)outp;
    void* args[7] = { &fp_in, &fp_h0, &fp_c0, &fp_wl, &fp_bl, &fp_ws, &fp_o };
    hipLaunchCooperativeKernel((const void*)k_lstm, dim3(256), dim3(NTHR),
                               args, LDS_BYTES, stream);
}